// Round 2
// baseline (1660.328 us; speedup 1.0000x reference)
//
#include <hip/hip_runtime.h>
#include <hip/hip_bf16.h>

// Spikformer block: 4x (dense GEMM + LN + LIF) + exact sparse spike-attention.
// All dense GEMMs in fp32 (no MFMA) to stay in the numpy-fp32 error class:
// LIF spikes are Heaviside steps; a flipped spike = absmax >= 1.0.

#define NB 4
#define LL 1024
#define DIM 1024
#define NH 16
#define HDIM 64
#define HID 4096
#define NROWS (NB * LL)

// ---------------- fp32 tiled GEMM: U = A @ W (+ colbias) ----------------
#define BM 128
#define BN 128
#define BK 16

__global__ __launch_bounds__(256) void gemm_f32(
    const float* __restrict__ A, const float* __restrict__ W,
    const float* __restrict__ bias, float* __restrict__ U,
    int M, int K, int N)
{
    __shared__ float As[BK][BM];
    __shared__ float Bs[BK][BN];
    const int t = threadIdx.x;
    const int tx = t & 15, ty = t >> 4;
    const int row0 = blockIdx.y * BM, col0 = blockIdx.x * BN;
    // A tile load mapping: 128x16 floats, 2 float4 per thread
    const int ar = t >> 2;            // 0..63
    const int ac = (t & 3) << 2;      // 0,4,8,12
    // B tile load mapping: 16x128 floats, 2 float4 per thread
    const int br = t >> 5;            // 0..7
    const int bc = (t & 31) << 2;     // 0..124
    float acc[8][8];
#pragma unroll
    for (int i = 0; i < 8; ++i)
#pragma unroll
        for (int j = 0; j < 8; ++j) acc[i][j] = 0.f;

    for (int k0 = 0; k0 < K; k0 += BK) {
        float4 a0 = *(const float4*)(A + (size_t)(row0 + ar) * K + k0 + ac);
        float4 a1 = *(const float4*)(A + (size_t)(row0 + ar + 64) * K + k0 + ac);
        float4 b0 = *(const float4*)(W + (size_t)(k0 + br) * N + col0 + bc);
        float4 b1 = *(const float4*)(W + (size_t)(k0 + br + 8) * N + col0 + bc);
        __syncthreads();   // previous iteration's LDS reads complete
        As[ac + 0][ar] = a0.x; As[ac + 1][ar] = a0.y;
        As[ac + 2][ar] = a0.z; As[ac + 3][ar] = a0.w;
        As[ac + 0][ar + 64] = a1.x; As[ac + 1][ar + 64] = a1.y;
        As[ac + 2][ar + 64] = a1.z; As[ac + 3][ar + 64] = a1.w;
        *(float4*)&Bs[br][bc] = b0;
        *(float4*)&Bs[br + 8][bc] = b1;
        __syncthreads();
#pragma unroll
        for (int kk = 0; kk < BK; ++kk) {
            float4 fa0 = *(float4*)&As[kk][ty * 8];
            float4 fa1 = *(float4*)&As[kk][ty * 8 + 4];
            float4 fb0 = *(float4*)&Bs[kk][tx * 8];
            float4 fb1 = *(float4*)&Bs[kk][tx * 8 + 4];
            float av[8] = {fa0.x, fa0.y, fa0.z, fa0.w, fa1.x, fa1.y, fa1.z, fa1.w};
            float bv[8] = {fb0.x, fb0.y, fb0.z, fb0.w, fb1.x, fb1.y, fb1.z, fb1.w};
#pragma unroll
            for (int i = 0; i < 8; ++i)
#pragma unroll
                for (int j = 0; j < 8; ++j)
                    acc[i][j] += av[i] * bv[j];
        }
    }
    float bvals[8];
#pragma unroll
    for (int j = 0; j < 8; ++j)
        bvals[j] = bias ? bias[col0 + tx * 8 + j] : 0.f;
#pragma unroll
    for (int i = 0; i < 8; ++i) {
        const int row = row0 + ty * 8 + i;
        float* dst = U + (size_t)row * N + col0 + tx * 8;
        float4 o0, o1;
        o0.x = acc[i][0] + bvals[0]; o0.y = acc[i][1] + bvals[1];
        o0.z = acc[i][2] + bvals[2]; o0.w = acc[i][3] + bvals[3];
        o1.x = acc[i][4] + bvals[4]; o1.y = acc[i][5] + bvals[5];
        o1.z = acc[i][6] + bvals[6]; o1.w = acc[i][7] + bvals[7];
        *(float4*)dst = o0;
        *(float4*)(dst + 4) = o1;
    }
}

// ---------------- fused LayerNorm + LIF (+ optional residual) ----------------
// spike = ((u - mean) * rsqrt(var + eps) * g + beta) >= thr   (thr = 2*v_th)
// out = resid ? resid + spike : spike
template <int DN>
__global__ __launch_bounds__(256) void lnlif_kernel(
    const float* __restrict__ U, const float* __restrict__ g,
    const float* __restrict__ beta, float thr,
    const float* __restrict__ resid, float* __restrict__ out)
{
    constexpr int PT = DN / 256;
    const int r = blockIdx.x, t = threadIdx.x;
    const float* u = U + (size_t)r * DN;
    float vals[PT];
    float lsum = 0.f;
#pragma unroll
    for (int i = 0; i < PT; ++i) {
        vals[i] = u[t + i * 256];
        lsum += vals[i];
    }
    __shared__ float red[4];
    __shared__ float bc0;
    for (int o = 32; o > 0; o >>= 1) lsum += __shfl_down(lsum, o);
    if ((t & 63) == 0) red[t >> 6] = lsum;
    __syncthreads();
    if (t == 0) bc0 = (red[0] + red[1] + red[2] + red[3]) * (1.f / DN);
    __syncthreads();
    const float m = bc0;
    float lss = 0.f;
#pragma unroll
    for (int i = 0; i < PT; ++i) {
        float d = vals[i] - m;
        lss += d * d;
    }
    for (int o = 32; o > 0; o >>= 1) lss += __shfl_down(lss, o);
    if ((t & 63) == 0) red[t >> 6] = lss;
    __syncthreads();
    if (t == 0) bc0 = (red[0] + red[1] + red[2] + red[3]) * (1.f / DN);
    __syncthreads();
    const float var = bc0;
    const float rs = 1.0f / sqrtf(var + 1e-5f);
#pragma unroll
    for (int i = 0; i < PT; ++i) {
        const int c = t + i * 256;
        const float nrm = (vals[i] - m) * rs * g[c] + beta[c];
        const float s = (nrm >= thr) ? 1.0f : 0.0f;
        out[(size_t)r * DN + c] = resid ? (resid[(size_t)r * DN + c] + s) : s;
    }
}

// ---------------- ktv[b,h,i,j] = sum_l Sk[b,l,h*64+i] * Sv[b,l,h*64+j] ----------------
// Binary spikes -> integer counts <= 1024 -> exact in fp32.
__global__ __launch_bounds__(256) void ktv_kernel(
    const float* __restrict__ Sk, const float* __restrict__ Sv,
    float* __restrict__ ktvb)
{
    const int bh = blockIdx.x;
    const int b = bh >> 4, h = bh & 15;
    __shared__ float kch[64][64];
    __shared__ float vch[64][64];
    const int t = threadIdx.x;
    const int i = t >> 2;           // 0..63
    const int j0 = (t & 3) << 4;    // 0,16,32,48
    float4 acc0 = {0, 0, 0, 0}, acc1 = {0, 0, 0, 0};
    float4 acc2 = {0, 0, 0, 0}, acc3 = {0, 0, 0, 0};
    for (int l0 = 0; l0 < LL; l0 += 64) {
        __syncthreads();
#pragma unroll
        for (int q = 0; q < 4; ++q) {
            const int idx = t + q * 256;
            const int li = idx >> 4, c4 = (idx & 15) << 2;
            const size_t off = ((size_t)b * LL + l0 + li) * DIM + h * HDIM + c4;
            *(float4*)&kch[li][c4] = *(const float4*)(Sk + off);
            *(float4*)&vch[li][c4] = *(const float4*)(Sv + off);
        }
        __syncthreads();
        for (int l = 0; l < 64; ++l) {
            const float kv = kch[l][i];
            if (kv != 0.f) {   // spike==1 -> just add v row segment
                const float4 v0 = *(float4*)&vch[l][j0];
                const float4 v1 = *(float4*)&vch[l][j0 + 4];
                const float4 v2 = *(float4*)&vch[l][j0 + 8];
                const float4 v3 = *(float4*)&vch[l][j0 + 12];
                acc0.x += v0.x; acc0.y += v0.y; acc0.z += v0.z; acc0.w += v0.w;
                acc1.x += v1.x; acc1.y += v1.y; acc1.z += v1.z; acc1.w += v1.w;
                acc2.x += v2.x; acc2.y += v2.y; acc2.z += v2.z; acc2.w += v2.w;
                acc3.x += v3.x; acc3.y += v3.y; acc3.z += v3.z; acc3.w += v3.w;
            }
        }
    }
    const size_t o = ((size_t)bh * 64 + i) * 64 + j0;
    *(float4*)(ktvb + o) = acc0;
    *(float4*)(ktvb + o + 4) = acc1;
    *(float4*)(ktvb + o + 8) = acc2;
    *(float4*)(ktvb + o + 12) = acc3;
}

// ---------------- y = 0.125 * Sq @ ktv; spike = (y >= 1.0) ----------------
// Sq binary; use ballot mask per row; all arithmetic exact.
__global__ __launch_bounds__(256) void qktv_kernel(
    const float* __restrict__ Sq, const float* __restrict__ ktvb,
    float* __restrict__ Y)
{
    const int bh = blockIdx.x;
    const int b = bh >> 4, h = bh & 15;
    __shared__ float kt[64][64];
    const int t = threadIdx.x;
#pragma unroll
    for (int q = 0; q < 16; ++q) {
        const int idx = t + q * 256;
        ((float*)kt)[idx] = ktvb[(size_t)bh * 4096 + idx];
    }
    __syncthreads();
    const int li = t >> 6;   // wave id: 4 rows per iteration
    const int j = t & 63;    // lane id = output dim
    for (int l0 = 0; l0 < LL; l0 += 4) {
        const size_t roff = ((size_t)b * LL + l0 + li) * DIM + h * HDIM;
        const float sqv = Sq[roff + j];
        unsigned long long mask = __ballot(sqv != 0.f);
        float acc = 0.f;
        while (mask) {
            const int i = __ffsll((unsigned long long)mask) - 1;
            mask &= mask - 1;
            acc += kt[i][j];
        }
        const float y = 0.125f * acc;
        Y[roff + j] = (y >= 1.0f) ? 1.0f : 0.0f;
    }
}

extern "C" void kernel_launch(void* const* d_in, const int* in_sizes, int n_in,
                              void* d_out, int out_size, void* d_ws, size_t ws_size,
                              hipStream_t stream)
{
    const float* x        = (const float*)d_in[0];
    const float* q_w      = (const float*)d_in[1];
    const float* q_g      = (const float*)d_in[2];
    const float* q_b      = (const float*)d_in[3];
    const float* k_w      = (const float*)d_in[4];
    const float* k_g      = (const float*)d_in[5];
    const float* k_b      = (const float*)d_in[6];
    const float* v_w      = (const float*)d_in[7];
    const float* v_g      = (const float*)d_in[8];
    const float* v_b      = (const float*)d_in[9];
    const float* proj_w   = (const float*)d_in[10];
    const float* proj_bias= (const float*)d_in[11];
    const float* proj_g   = (const float*)d_in[12];
    const float* proj_beta= (const float*)d_in[13];
    const float* fc1_w    = (const float*)d_in[14];
    const float* fc1_bias = (const float*)d_in[15];
    const float* fc1_g    = (const float*)d_in[16];
    const float* fc1_beta = (const float*)d_in[17];
    const float* fc2_w    = (const float*)d_in[18];
    const float* fc2_bias = (const float*)d_in[19];
    const float* fc2_g    = (const float*)d_in[20];
    const float* fc2_beta = (const float*)d_in[21];

    // Workspace layout (floats), aliased to minimize footprint (~81 MB):
    //   U:  [0 .. NROWS*HID) — 64 MB, full size needed only from fc1 onward.
    //     During QKV/attention only U[0 .. NROWS*DIM) is live, so:
    //     Sq = U + 1*NROWS*DIM, Sk = U + 2*NROWS*DIM, Sv = U + 3*NROWS*DIM.
    //     Yb (attention spikes) aliases Sv (dead after ktv_kernel).
    //   ktvb: after U (1 MB).  Y2 (fc2 out): after ktvb (16 MB).
    //   X1 (residual-1) lives in d_out; final lnlif reads it as resid and
    //   overwrites d_out element-wise (read-before-write per element).
    float* U    = (float*)d_ws;
    float* Sq   = U + (size_t)1 * NROWS * DIM;
    float* Sk   = U + (size_t)2 * NROWS * DIM;
    float* Sv   = U + (size_t)3 * NROWS * DIM;
    float* Yb   = Sv;  // alias: qktv writes after ktv_kernel consumed Sv
    float* ktvb = U + (size_t)NROWS * HID;
    float* Y2   = ktvb + (size_t)NB * NH * HDIM * HDIM;
    float* X1   = (float*)d_out;
    float* outf = (float*)d_out;

    const dim3 blk(256);
    const dim3 gemm_d(DIM / BN, NROWS / BM);    // (8, 32)
    const dim3 gemm_h(HID / BN, NROWS / BM);    // (32, 32)

    // q, k, v projections + LN + LIF
    gemm_f32<<<gemm_d, blk, 0, stream>>>(x, q_w, nullptr, U, NROWS, DIM, DIM);
    lnlif_kernel<DIM><<<NROWS, blk, 0, stream>>>(U, q_g, q_b, 2.0f, nullptr, Sq);
    gemm_f32<<<gemm_d, blk, 0, stream>>>(x, k_w, nullptr, U, NROWS, DIM, DIM);
    lnlif_kernel<DIM><<<NROWS, blk, 0, stream>>>(U, k_g, k_b, 2.0f, nullptr, Sk);
    gemm_f32<<<gemm_d, blk, 0, stream>>>(x, v_w, nullptr, U, NROWS, DIM, DIM);
    lnlif_kernel<DIM><<<NROWS, blk, 0, stream>>>(U, v_g, v_b, 2.0f, nullptr, Sv);

    // exact spike attention: y = 0.125 * q @ (k^T @ v); attn-LIF (v_th=0.5 -> y>=1.0)
    ktv_kernel<<<NB * NH, blk, 0, stream>>>(Sk, Sv, ktvb);
    qktv_kernel<<<NB * NH, blk, 0, stream>>>(Sq, ktvb, Yb);

    // proj + LN + LIF, fused residual: X1 = x + spike
    gemm_f32<<<gemm_d, blk, 0, stream>>>(Yb, proj_w, proj_bias, U, NROWS, DIM, DIM);
    lnlif_kernel<DIM><<<NROWS, blk, 0, stream>>>(U, proj_g, proj_beta, 2.0f, x, X1);

    // fc1 + LN + LIF (in-place spike into U; overwrites Sq/Sk/Sv/Yb aliases)
    gemm_f32<<<gemm_h, blk, 0, stream>>>(X1, fc1_w, fc1_bias, U, NROWS, DIM, HID);
    lnlif_kernel<HID><<<NROWS, blk, 0, stream>>>(U, fc1_g, fc1_beta, 2.0f, nullptr, U);

    // fc2 + LN + LIF, fused residual: out = X1 + spike
    gemm_f32<<<gemm_d, blk, 0, stream>>>(U, fc2_w, fc2_bias, Y2, NROWS, HID, DIM);
    lnlif_kernel<DIM><<<NROWS, blk, 0, stream>>>(Y2, fc2_g, fc2_beta, 2.0f, X1, outf);
}

// Round 4
// 1146.550 us; speedup vs baseline: 1.4481x; 1.4481x over previous
//
#include <hip/hip_runtime.h>
#include <hip/hip_bf16.h>

// Spikformer block on MI355X.
// Fast path: exact bf16-split MFMA GEMMs (fp32 = 3 bf16 planes; 6 products for
// fp32 x fp32, 3 products for binary-spike x fp32) + fused LN+LIF + exact
// sparse spike-attention (0.125 * q @ (k^T @ v), integer counts).
// Fallback path (ws_size too small): round-2 fp32 VALU pipeline (verified).
//
// R4 fix: explicit s_waitcnt lgkmcnt(0)/vmcnt(0) before the two barriers in
// gemm_mfma — cross-wave LDS visibility of global_load_lds must not rely on
// the compiler's drain placement (replay-only spike-flip race in R3).

#define NB 4
#define LL 1024
#define DIM 1024
#define NH 16
#define HDIM 64
#define HID 4096
#define NROWS (NB * LL)

typedef unsigned short u16;
typedef __attribute__((ext_vector_type(8))) short short8v;   // 8 bf16 (4 VGPRs)
typedef __attribute__((ext_vector_type(4))) float f32x4;     // MFMA acc

// ---------------- bf16 split helpers (RNE; split is exact by construction) ---
__device__ __forceinline__ u16 f2bf(float f) {
    unsigned u = __builtin_bit_cast(unsigned, f);
    return (u16)((u + 0x7fffu + ((u >> 16) & 1u)) >> 16);
}
__device__ __forceinline__ float bf2f(u16 h) {
    unsigned u = ((unsigned)h) << 16;
    return __builtin_bit_cast(float, u);
}
__device__ __forceinline__ void split3v(float v, u16& a, u16& b, u16& c) {
    a = f2bf(v);
    float r = v - bf2f(a);
    b = f2bf(r);
    float r2 = r - bf2f(b);
    c = f2bf(r2);
}

// ---------------- split x (f32 [M][K]) -> planes bf16 [M][3K] ----------------
__global__ __launch_bounds__(256) void split3_rows(
    const float* __restrict__ X, u16* __restrict__ Xs, int K)
{
    const int row = blockIdx.y;
    const int c4 = (blockIdx.x * 256 + threadIdx.x) * 4;
    if (c4 >= K) return;
    float4 v = *(const float4*)(X + (size_t)row * K + c4);
    float vv[4] = {v.x, v.y, v.z, v.w};
    u16 h0[4], h1[4], h2[4];
#pragma unroll
    for (int j = 0; j < 4; ++j) split3v(vv[j], h0[j], h1[j], h2[j]);
    u16* base = Xs + (size_t)row * 3 * K + c4;
    *(uint2*)(base + 0 * K) = *(uint2*)h0;
    *(uint2*)(base + 1 * K) = *(uint2*)h1;
    *(uint2*)(base + 2 * K) = *(uint2*)h2;
}

// ------------- split + transpose W (f32 [K][N]) -> Wt bf16 [N][3K] -----------
__global__ __launch_bounds__(256) void split_wt(
    const float* __restrict__ W, u16* __restrict__ Wt, int K, int N)
{
    __shared__ float tile[64][65];   // [n][k], padded
    const int k0 = blockIdx.y * 64, n0 = blockIdx.x * 64;
    const int t = threadIdx.x;
    const int rr = t >> 4;            // 0..15 (k within chunk)
    const int cc = (t & 15) * 4;      // 0..60 (n)
#pragma unroll
    for (int it = 0; it < 4; ++it) {
        const int k = rr + it * 16;
        float4 v = *(const float4*)(W + (size_t)(k0 + k) * N + n0 + cc);
        tile[cc + 0][k] = v.x; tile[cc + 1][k] = v.y;
        tile[cc + 2][k] = v.z; tile[cc + 3][k] = v.w;
    }
    __syncthreads();
    const int n = t >> 2, kc = (t & 3) * 16;
    u16 h0[16], h1[16], h2[16];
#pragma unroll
    for (int j = 0; j < 16; ++j)
        split3v(tile[n][kc + j], h0[j], h1[j], h2[j]);
    u16* base = Wt + (size_t)(n0 + n) * (3 * K) + k0 + kc;
    *(uint4*)(base + 0 * K)     = ((uint4*)h0)[0];
    *(uint4*)(base + 0 * K + 8) = ((uint4*)h0)[1];
    *(uint4*)(base + 1 * K)     = ((uint4*)h1)[0];
    *(uint4*)(base + 1 * K + 8) = ((uint4*)h1)[1];
    *(uint4*)(base + 2 * K)     = ((uint4*)h2)[0];
    *(uint4*)(base + 2 * K + 8) = ((uint4*)h2)[1];
}

// ---------------- MFMA GEMM: Out(f32) = sum_segs A[:,a+k] * Bt[:,b+k]^T ------
// A bf16 [M][lda] row-major; Bt bf16 [N][ldb] (output-col-major, k contiguous).
// 128xBN_ tile, 4 waves, 16x16x32 bf16 MFMA, global_load_lds staging (m97).
struct SegList { int a[6]; int b[6]; int n; };

template <int BN_>
__global__ __launch_bounds__(256) void gemm_mfma(
    const u16* __restrict__ A, int lda,
    const u16* __restrict__ Bt, int ldb,
    SegList segs, int Kseg,
    const float* __restrict__ bias,
    float* __restrict__ Out, int ldo)
{
    constexpr int NF = BN_ / 32;              // B-frags per wave
    __shared__ u16 As[128 * 32];
    __shared__ u16 Bs[BN_ * 32];
    const int t = threadIdx.x;
    const int wid = t >> 6, lane = t & 63;
    const int wr = wid >> 1, wc = wid & 1;
    const int row0 = blockIdx.y * 128, col0 = blockIdx.x * BN_;
    const int sr = lane >> 2;                 // staging row in 16-row chunk
    const int sc = (lane & 3) * 8;            // staging col (elems)
    const int lrow = lane & 15, lk8 = (lane >> 4) * 8;

    f32x4 acc[4][NF];
#pragma unroll
    for (int i = 0; i < 4; ++i)
#pragma unroll
        for (int j = 0; j < NF; ++j) acc[i][j] = f32x4{0.f, 0.f, 0.f, 0.f};

    for (int s = 0; s < segs.n; ++s) {
        const u16* pa = A + segs.a[s];
        const u16* pb = Bt + segs.b[s];
        for (int k0 = 0; k0 < Kseg; k0 += 32) {
            // All frag ds_reads of the previous iteration must be retired in
            // EVERY wave before any wave's DMA overwrites LDS.
            asm volatile("s_waitcnt lgkmcnt(0)" ::: "memory");
            __syncthreads();
#pragma unroll
            for (int c = 0; c < 2; ++c) {      // A tile: 8 KB, 2 chunks/wave
                const int chunk = wid * 2 + c;
                const int r = chunk * 16 + sr;
                __builtin_amdgcn_global_load_lds(
                    (const __attribute__((address_space(1))) void*)
                        (pa + (size_t)(row0 + r) * lda + k0 + sc),
                    (__attribute__((address_space(3))) void*)
                        (&As[chunk * 512 + lane * 8]),
                    16, 0, 0);
            }
#pragma unroll
            for (int c = 0; c < BN_ / 64; ++c) {   // B tile
                const int chunk = wid * (BN_ / 64) + c;
                const int r = chunk * 16 + sr;
                __builtin_amdgcn_global_load_lds(
                    (const __attribute__((address_space(1))) void*)
                        (pb + (size_t)(col0 + r) * ldb + k0 + sc),
                    (__attribute__((address_space(3))) void*)
                        (&Bs[chunk * 512 + lane * 8]),
                    16, 0, 0);
            }
            // All async LDS-DMA of THIS wave must land before the barrier so
            // that after the barrier every wave sees every wave's staging.
            asm volatile("s_waitcnt vmcnt(0)" ::: "memory");
            __syncthreads();
            short8v af[4], bfr[NF];
#pragma unroll
            for (int f = 0; f < 4; ++f)
                af[f] = *(const short8v*)&As[(wr * 64 + f * 16 + lrow) * 32 + lk8];
#pragma unroll
            for (int f = 0; f < NF; ++f)
                bfr[f] = *(const short8v*)&Bs[(wc * (BN_ / 2) + f * 16 + lrow) * 32 + lk8];
#pragma unroll
            for (int i = 0; i < 4; ++i)
#pragma unroll
                for (int j = 0; j < NF; ++j)
                    acc[i][j] = __builtin_amdgcn_mfma_f32_16x16x32_bf16(
                        af[i], bfr[j], acc[i][j], 0, 0, 0);
        }
    }
    // epilogue: C/D layout col=lane&15, row=(lane>>4)*4+reg  [m89-verified]
#pragma unroll
    for (int j = 0; j < NF; ++j) {
        const int col = col0 + wc * (BN_ / 2) + j * 16 + lrow;
        const float bv = bias ? bias[col] : 0.f;
#pragma unroll
        for (int i = 0; i < 4; ++i) {
            const int rbase = row0 + wr * 64 + i * 16 + (lane >> 4) * 4;
#pragma unroll
            for (int r = 0; r < 4; ++r)
                Out[(size_t)(rbase + r) * ldo + col] = acc[i][j][r] + bv;
        }
    }
}

// ---------------- fused LN + LIF, multi-output ------------------------------
// spike = (LN(u)*g+beta >= 2.0). Optional outputs: spike as bf16; f32 resid+spike;
// 3-plane bf16 split of resid+spike (for the next x-driven GEMM).
template <int DN>
__global__ __launch_bounds__(256) void lnlif2(
    const float* __restrict__ U, const float* __restrict__ g,
    const float* __restrict__ beta,
    const float* __restrict__ resid,
    u16* __restrict__ spike_bf16,
    float* __restrict__ out_f32,
    u16* __restrict__ split3_out)
{
    constexpr int PT = DN / 256;
    const int r = blockIdx.x, t = threadIdx.x;
    const float* u = U + (size_t)r * DN;
    float vals[PT];
    float lsum = 0.f;
#pragma unroll
    for (int i = 0; i < PT; ++i) { vals[i] = u[t + i * 256]; lsum += vals[i]; }
    __shared__ float red[4];
    __shared__ float bcast;
    for (int o = 32; o > 0; o >>= 1) lsum += __shfl_down(lsum, o);
    if ((t & 63) == 0) red[t >> 6] = lsum;
    __syncthreads();
    if (t == 0) bcast = (red[0] + red[1] + red[2] + red[3]) * (1.f / DN);
    __syncthreads();
    const float m = bcast;
    float lss = 0.f;
#pragma unroll
    for (int i = 0; i < PT; ++i) { float d = vals[i] - m; lss += d * d; }
    for (int o = 32; o > 0; o >>= 1) lss += __shfl_down(lss, o);
    if ((t & 63) == 0) red[t >> 6] = lss;
    __syncthreads();
    if (t == 0) bcast = (red[0] + red[1] + red[2] + red[3]) * (1.f / DN);
    __syncthreads();
    const float rs = 1.f / sqrtf(bcast + 1e-5f);
#pragma unroll
    for (int i = 0; i < PT; ++i) {
        const int c = t + i * 256;
        const size_t idx = (size_t)r * DN + c;
        const float nrm = (vals[i] - m) * rs * g[c] + beta[c];
        const float s = (nrm >= 2.0f) ? 1.0f : 0.0f;
        if (spike_bf16) spike_bf16[idx] = s != 0.f ? (u16)0x3F80 : (u16)0;
        if (out_f32 || split3_out) {
            const float v = (resid ? resid[idx] : 0.f) + s;
            if (out_f32) out_f32[idx] = v;
            if (split3_out) {
                u16 h0, h1, h2; split3v(v, h0, h1, h2);
                split3_out[(size_t)r * 3 * DN + 0 * DN + c] = h0;
                split3_out[(size_t)r * 3 * DN + 1 * DN + c] = h1;
                split3_out[(size_t)r * 3 * DN + 2 * DN + c] = h2;
            }
        }
    }
}

// ---------------- attention: ktv (bf16 spikes) ------------------------------
__global__ __launch_bounds__(256) void ktv_bf16(
    const u16* __restrict__ Sk, const u16* __restrict__ Sv,
    float* __restrict__ ktvb)
{
    const int bh = blockIdx.x;
    const int b = bh >> 4, h = bh & 15;
    __shared__ float kch[64][64];
    __shared__ float vch[64][64];
    const int t = threadIdx.x;
    const int i = t >> 2;
    const int j0 = (t & 3) << 4;
    float4 a0 = {0,0,0,0}, a1 = {0,0,0,0}, a2 = {0,0,0,0}, a3 = {0,0,0,0};
    for (int l0 = 0; l0 < LL; l0 += 64) {
        __syncthreads();
#pragma unroll
        for (int q = 0; q < 2; ++q) {
            const int chunk = t + q * 256;           // 512 chunks of 8 elems
            const int li = chunk >> 3, c8 = (chunk & 7) << 3;
            const size_t off = ((size_t)b * LL + l0 + li) * DIM + h * HDIM + c8;
            union { uint4 v; u16 s[8]; } uk, uv;
            uk.v = *(const uint4*)(Sk + off);
            uv.v = *(const uint4*)(Sv + off);
#pragma unroll
            for (int j = 0; j < 8; ++j) {
                kch[li][c8 + j] = uk.s[j] ? 1.f : 0.f;
                vch[li][c8 + j] = uv.s[j] ? 1.f : 0.f;
            }
        }
        __syncthreads();
        for (int l = 0; l < 64; ++l) {
            if (kch[l][i] != 0.f) {
                const float4 v0 = *(float4*)&vch[l][j0];
                const float4 v1 = *(float4*)&vch[l][j0 + 4];
                const float4 v2 = *(float4*)&vch[l][j0 + 8];
                const float4 v3 = *(float4*)&vch[l][j0 + 12];
                a0.x += v0.x; a0.y += v0.y; a0.z += v0.z; a0.w += v0.w;
                a1.x += v1.x; a1.y += v1.y; a1.z += v1.z; a1.w += v1.w;
                a2.x += v2.x; a2.y += v2.y; a2.z += v2.z; a2.w += v2.w;
                a3.x += v3.x; a3.y += v3.y; a3.z += v3.z; a3.w += v3.w;
            }
        }
    }
    const size_t o = ((size_t)bh * 64 + i) * 64 + j0;
    *(float4*)(ktvb + o)      = a0;
    *(float4*)(ktvb + o + 4)  = a1;
    *(float4*)(ktvb + o + 8)  = a2;
    *(float4*)(ktvb + o + 12) = a3;
}

// ---------------- attention: q@(ktv), LIF(v_th=0.5), bf16 spikes out --------
__global__ __launch_bounds__(256) void qktv_bf16(
    const u16* __restrict__ Sq, const float* __restrict__ ktvb,
    u16* __restrict__ Y)
{
    const int bh = blockIdx.x;
    const int b = bh >> 4, h = bh & 15;
    __shared__ float kt[64][64];
    const int t = threadIdx.x;
#pragma unroll
    for (int q = 0; q < 16; ++q) {
        const int idx = t + q * 256;
        ((float*)kt)[idx] = ktvb[(size_t)bh * 4096 + idx];
    }
    __syncthreads();
    const int li = t >> 6;
    const int j = t & 63;
    for (int l0 = 0; l0 < LL; l0 += 4) {
        const size_t roff = ((size_t)b * LL + l0 + li) * DIM + h * HDIM;
        const u16 sqv = Sq[roff + j];
        unsigned long long mask = __ballot(sqv != 0);
        float acc = 0.f;
        while (mask) {
            const int i = __ffsll((unsigned long long)mask) - 1;
            mask &= mask - 1;
            acc += kt[i][j];
        }
        const float y = 0.125f * acc;
        Y[roff + j] = (y >= 1.0f) ? (u16)0x3F80 : (u16)0;
    }
}

// ======================= FALLBACK (round-2 fp32 path) ========================
#define BM 128
#define BN 128
#define BK 16

__global__ __launch_bounds__(256) void gemm_f32(
    const float* __restrict__ A, const float* __restrict__ W,
    const float* __restrict__ bias, float* __restrict__ U,
    int M, int K, int N)
{
    __shared__ float As[BK][BM];
    __shared__ float Bs[BK][BN];
    const int t = threadIdx.x;
    const int tx = t & 15, ty = t >> 4;
    const int row0 = blockIdx.y * BM, col0 = blockIdx.x * BN;
    const int ar = t >> 2;
    const int ac = (t & 3) << 2;
    const int br = t >> 5;
    const int bc = (t & 31) << 2;
    float acc[8][8];
#pragma unroll
    for (int i = 0; i < 8; ++i)
#pragma unroll
        for (int j = 0; j < 8; ++j) acc[i][j] = 0.f;
    for (int k0 = 0; k0 < K; k0 += BK) {
        float4 va0 = *(const float4*)(A + (size_t)(row0 + ar) * K + k0 + ac);
        float4 va1 = *(const float4*)(A + (size_t)(row0 + ar + 64) * K + k0 + ac);
        float4 vb0 = *(const float4*)(W + (size_t)(k0 + br) * N + col0 + bc);
        float4 vb1 = *(const float4*)(W + (size_t)(k0 + br + 8) * N + col0 + bc);
        __syncthreads();
        As[ac + 0][ar] = va0.x; As[ac + 1][ar] = va0.y;
        As[ac + 2][ar] = va0.z; As[ac + 3][ar] = va0.w;
        As[ac + 0][ar + 64] = va1.x; As[ac + 1][ar + 64] = va1.y;
        As[ac + 2][ar + 64] = va1.z; As[ac + 3][ar + 64] = va1.w;
        *(float4*)&Bs[br][bc] = vb0;
        *(float4*)&Bs[br + 8][bc] = vb1;
        __syncthreads();
#pragma unroll
        for (int kk = 0; kk < BK; ++kk) {
            float4 fa0 = *(float4*)&As[kk][ty * 8];
            float4 fa1 = *(float4*)&As[kk][ty * 8 + 4];
            float4 fb0 = *(float4*)&Bs[kk][tx * 8];
            float4 fb1 = *(float4*)&Bs[kk][tx * 8 + 4];
            float av[8] = {fa0.x, fa0.y, fa0.z, fa0.w, fa1.x, fa1.y, fa1.z, fa1.w};
            float bv[8] = {fb0.x, fb0.y, fb0.z, fb0.w, fb1.x, fb1.y, fb1.z, fb1.w};
#pragma unroll
            for (int i = 0; i < 8; ++i)
#pragma unroll
                for (int j = 0; j < 8; ++j)
                    acc[i][j] += av[i] * bv[j];
        }
    }
    float bvals[8];
#pragma unroll
    for (int j = 0; j < 8; ++j)
        bvals[j] = bias ? bias[col0 + tx * 8 + j] : 0.f;
#pragma unroll
    for (int i = 0; i < 8; ++i) {
        const int row = row0 + ty * 8 + i;
        float* dst = U + (size_t)row * N + col0 + tx * 8;
        float4 o0, o1;
        o0.x = acc[i][0] + bvals[0]; o0.y = acc[i][1] + bvals[1];
        o0.z = acc[i][2] + bvals[2]; o0.w = acc[i][3] + bvals[3];
        o1.x = acc[i][4] + bvals[4]; o1.y = acc[i][5] + bvals[5];
        o1.z = acc[i][6] + bvals[6]; o1.w = acc[i][7] + bvals[7];
        *(float4*)dst = o0;
        *(float4*)(dst + 4) = o1;
    }
}

template <int DN>
__global__ __launch_bounds__(256) void lnlif_old(
    const float* __restrict__ U, const float* __restrict__ g,
    const float* __restrict__ beta, float thr,
    const float* __restrict__ resid, float* __restrict__ out)
{
    constexpr int PT = DN / 256;
    const int r = blockIdx.x, t = threadIdx.x;
    const float* u = U + (size_t)r * DN;
    float vals[PT];
    float lsum = 0.f;
#pragma unroll
    for (int i = 0; i < PT; ++i) { vals[i] = u[t + i * 256]; lsum += vals[i]; }
    __shared__ float red[4];
    __shared__ float bc0;
    for (int o = 32; o > 0; o >>= 1) lsum += __shfl_down(lsum, o);
    if ((t & 63) == 0) red[t >> 6] = lsum;
    __syncthreads();
    if (t == 0) bc0 = (red[0] + red[1] + red[2] + red[3]) * (1.f / DN);
    __syncthreads();
    const float m = bc0;
    float lss = 0.f;
#pragma unroll
    for (int i = 0; i < PT; ++i) { float d = vals[i] - m; lss += d * d; }
    for (int o = 32; o > 0; o >>= 1) lss += __shfl_down(lss, o);
    if ((t & 63) == 0) red[t >> 6] = lss;
    __syncthreads();
    if (t == 0) bc0 = (red[0] + red[1] + red[2] + red[3]) * (1.f / DN);
    __syncthreads();
    const float rs = 1.0f / sqrtf(bc0 + 1e-5f);
#pragma unroll
    for (int i = 0; i < PT; ++i) {
        const int c = t + i * 256;
        const float nrm = (vals[i] - m) * rs * g[c] + beta[c];
        const float s = (nrm >= thr) ? 1.0f : 0.0f;
        out[(size_t)r * DN + c] = resid ? (resid[(size_t)r * DN + c] + s) : s;
    }
}

__global__ __launch_bounds__(256) void ktv_f32(
    const float* __restrict__ Sk, const float* __restrict__ Sv,
    float* __restrict__ ktvb)
{
    const int bh = blockIdx.x;
    const int b = bh >> 4, h = bh & 15;
    __shared__ float kch[64][64];
    __shared__ float vch[64][64];
    const int t = threadIdx.x;
    const int i = t >> 2;
    const int j0 = (t & 3) << 4;
    float4 a0 = {0,0,0,0}, a1 = {0,0,0,0}, a2 = {0,0,0,0}, a3 = {0,0,0,0};
    for (int l0 = 0; l0 < LL; l0 += 64) {
        __syncthreads();
#pragma unroll
        for (int q = 0; q < 4; ++q) {
            const int idx = t + q * 256;
            const int li = idx >> 4, c4 = (idx & 15) << 2;
            const size_t off = ((size_t)b * LL + l0 + li) * DIM + h * HDIM + c4;
            *(float4*)&kch[li][c4] = *(const float4*)(Sk + off);
            *(float4*)&vch[li][c4] = *(const float4*)(Sv + off);
        }
        __syncthreads();
        for (int l = 0; l < 64; ++l) {
            if (kch[l][i] != 0.f) {
                const float4 v0 = *(float4*)&vch[l][j0];
                const float4 v1 = *(float4*)&vch[l][j0 + 4];
                const float4 v2 = *(float4*)&vch[l][j0 + 8];
                const float4 v3 = *(float4*)&vch[l][j0 + 12];
                a0.x += v0.x; a0.y += v0.y; a0.z += v0.z; a0.w += v0.w;
                a1.x += v1.x; a1.y += v1.y; a1.z += v1.z; a1.w += v1.w;
                a2.x += v2.x; a2.y += v2.y; a2.z += v2.z; a2.w += v2.w;
                a3.x += v3.x; a3.y += v3.y; a3.z += v3.z; a3.w += v3.w;
            }
        }
    }
    const size_t o = ((size_t)bh * 64 + i) * 64 + j0;
    *(float4*)(ktvb + o)      = a0;
    *(float4*)(ktvb + o + 4)  = a1;
    *(float4*)(ktvb + o + 8)  = a2;
    *(float4*)(ktvb + o + 12) = a3;
}

__global__ __launch_bounds__(256) void qktv_f32(
    const float* __restrict__ Sq, const float* __restrict__ ktvb,
    float* __restrict__ Y)
{
    const int bh = blockIdx.x;
    const int b = bh >> 4, h = bh & 15;
    __shared__ float kt[64][64];
    const int t = threadIdx.x;
#pragma unroll
    for (int q = 0; q < 16; ++q) {
        const int idx = t + q * 256;
        ((float*)kt)[idx] = ktvb[(size_t)bh * 4096 + idx];
    }
    __syncthreads();
    const int li = t >> 6;
    const int j = t & 63;
    for (int l0 = 0; l0 < LL; l0 += 4) {
        const size_t roff = ((size_t)b * LL + l0 + li) * DIM + h * HDIM;
        const float sqv = Sq[roff + j];
        unsigned long long mask = __ballot(sqv != 0.f);
        float acc = 0.f;
        while (mask) {
            const int i = __ffsll((unsigned long long)mask) - 1;
            mask &= mask - 1;
            acc += kt[i][j];
        }
        const float y = 0.125f * acc;
        Y[roff + j] = (y >= 1.0f) ? 1.0f : 0.0f;
    }
}

// ============================== launch ======================================
extern "C" void kernel_launch(void* const* d_in, const int* in_sizes, int n_in,
                              void* d_out, int out_size, void* d_ws, size_t ws_size,
                              hipStream_t stream)
{
    const float* x        = (const float*)d_in[0];
    const float* q_w      = (const float*)d_in[1];
    const float* q_g      = (const float*)d_in[2];
    const float* q_b      = (const float*)d_in[3];
    const float* k_w      = (const float*)d_in[4];
    const float* k_g      = (const float*)d_in[5];
    const float* k_b      = (const float*)d_in[6];
    const float* v_w      = (const float*)d_in[7];
    const float* v_g      = (const float*)d_in[8];
    const float* v_b      = (const float*)d_in[9];
    const float* proj_w   = (const float*)d_in[10];
    const float* proj_bias= (const float*)d_in[11];
    const float* proj_g   = (const float*)d_in[12];
    const float* proj_beta= (const float*)d_in[13];
    const float* fc1_w    = (const float*)d_in[14];
    const float* fc1_bias = (const float*)d_in[15];
    const float* fc1_g    = (const float*)d_in[16];
    const float* fc1_beta = (const float*)d_in[17];
    const float* fc2_w    = (const float*)d_in[18];
    const float* fc2_bias = (const float*)d_in[19];
    const float* fc2_g    = (const float*)d_in[20];
    const float* fc2_beta = (const float*)d_in[21];

    const dim3 blk(256);
    const size_t NEEDED = 143654912;  // see layout below

    if (ws_size >= NEEDED) {
        // ---- fast path layout (bytes):
        //   U    f32  [0, 67108864)        GEMM outputs (full size only at fc1)
        //   Xsh  bf16 [67108864, +33554432) Xs planes / X1s planes / fc1 spikes
        //   Wbuf bf16 [100663296, +25165824) current weight planes (transposed)
        //   Sq   bf16 [125829120, +8388608)
        //   Sk   bf16 [134217728, +8388608)
        //   ktvb f32  [142606336, +1048576)
        //   SvYb bf16 = Xsh + 25165824 (spare 8 MB above Xs/X1s planes)
        //   X1   f32  = d_out (overwritten element-wise by final lnlif)
        char* ws = (char*)d_ws;
        float* U    = (float*)ws;
        u16*   Xsh  = (u16*)(ws + 67108864);
        u16*   Wbuf = (u16*)(ws + 100663296);
        u16*   Sq   = (u16*)(ws + 125829120);
        u16*   Sk   = (u16*)(ws + 134217728);
        float* ktvb = (float*)(ws + 142606336);
        u16*   SvYb = (u16*)((char*)Xsh + 25165824);
        u16*   Xs   = Xsh;          // [4096][3072]
        u16*   X1s  = Xsh;          // [4096][3072] (after Xs dead)
        u16*   Sm   = Xsh;          // [4096][4096] (after X1s dead)
        float* X1   = (float*)d_out;

        SegList segX;  // 6-product exact fp32xfp32: (0,0)(1,1)(2,0)(0,2)(1,0)(0,1)
        {
            const int pa[6] = {0, 1, 2, 0, 1, 0}, pb[6] = {0, 1, 0, 2, 0, 1};
            for (int i = 0; i < 6; ++i) { segX.a[i] = pa[i] * 1024; segX.b[i] = pb[i] * 1024; }
            segX.n = 6;
        }
        SegList segP;  // spike x fp32 (K=1024): A plane 0, B planes 0/1/2
        {
            for (int i = 0; i < 6; ++i) { segP.a[i] = 0; segP.b[i] = 0; }
            segP.b[1] = 1024; segP.b[2] = 2048; segP.n = 3;
        }
        SegList segF2; // spike x fp32 (K=4096)
        {
            for (int i = 0; i < 6; ++i) { segF2.a[i] = 0; segF2.b[i] = 0; }
            segF2.b[1] = 4096; segF2.b[2] = 8192; segF2.n = 3;
        }

        split3_rows<<<dim3(1, NROWS), blk, 0, stream>>>(x, Xs, DIM);

        // q, k, v
        split_wt<<<dim3(16, 16), blk, 0, stream>>>(q_w, Wbuf, DIM, DIM);
        gemm_mfma<64><<<dim3(16, 32), blk, 0, stream>>>(Xs, 3072, Wbuf, 3072, segX, 1024, nullptr, U, DIM);
        lnlif2<DIM><<<NROWS, blk, 0, stream>>>(U, q_g, q_b, nullptr, Sq, nullptr, nullptr);
        split_wt<<<dim3(16, 16), blk, 0, stream>>>(k_w, Wbuf, DIM, DIM);
        gemm_mfma<64><<<dim3(16, 32), blk, 0, stream>>>(Xs, 3072, Wbuf, 3072, segX, 1024, nullptr, U, DIM);
        lnlif2<DIM><<<NROWS, blk, 0, stream>>>(U, k_g, k_b, nullptr, Sk, nullptr, nullptr);
        split_wt<<<dim3(16, 16), blk, 0, stream>>>(v_w, Wbuf, DIM, DIM);
        gemm_mfma<64><<<dim3(16, 32), blk, 0, stream>>>(Xs, 3072, Wbuf, 3072, segX, 1024, nullptr, U, DIM);
        lnlif2<DIM><<<NROWS, blk, 0, stream>>>(U, v_g, v_b, nullptr, SvYb, nullptr, nullptr);

        // attention (exact): ktv counts, then 0.125*q@ktv, LIF v_th=0.5
        ktv_bf16<<<NB * NH, blk, 0, stream>>>(Sk, SvYb, ktvb);
        qktv_bf16<<<NB * NH, blk, 0, stream>>>(Sq, ktvb, SvYb);   // Yb aliases Sv

        // proj + LN + LIF; residual-1 into d_out (X1) + 3-plane split (X1s)
        split_wt<<<dim3(16, 16), blk, 0, stream>>>(proj_w, Wbuf, DIM, DIM);
        gemm_mfma<64><<<dim3(16, 32), blk, 0, stream>>>(SvYb, 1024, Wbuf, 3072, segP, 1024, proj_bias, U, DIM);
        lnlif2<DIM><<<NROWS, blk, 0, stream>>>(U, proj_g, proj_beta, x, nullptr, X1, X1s);

        // fc1 + LN + LIF (spikes bf16 into Sm, overwrites X1s)
        split_wt<<<dim3(64, 16), blk, 0, stream>>>(fc1_w, Wbuf, DIM, HID);
        gemm_mfma<128><<<dim3(32, 32), blk, 0, stream>>>(X1s, 3072, Wbuf, 3072, segX, 1024, fc1_bias, U, HID);
        lnlif2<HID><<<NROWS, blk, 0, stream>>>(U, fc1_g, fc1_beta, nullptr, Sm, nullptr, nullptr);

        // fc2 + LN + LIF + residual-2 -> d_out
        split_wt<<<dim3(16, 64), blk, 0, stream>>>(fc2_w, Wbuf, HID, DIM);
        gemm_mfma<64><<<dim3(16, 32), blk, 0, stream>>>(Sm, 4096, Wbuf, 12288, segF2, 4096, fc2_bias, U, DIM);
        lnlif2<DIM><<<NROWS, blk, 0, stream>>>(U, fc2_g, fc2_beta, X1, nullptr, (float*)d_out, nullptr);
        return;
    }

    // ---- fallback: round-2 fp32 path (verified; needs ~85 MB) ----
    float* U    = (float*)d_ws;
    float* Sq   = U + (size_t)1 * NROWS * DIM;
    float* Sk   = U + (size_t)2 * NROWS * DIM;
    float* Sv   = U + (size_t)3 * NROWS * DIM;
    float* Yb   = Sv;
    float* ktvb = U + (size_t)NROWS * HID;
    float* Y2   = ktvb + (size_t)NB * NH * HDIM * HDIM;
    float* X1   = (float*)d_out;
    float* outf = (float*)d_out;

    const dim3 gemm_d(DIM / BN, NROWS / BM);
    const dim3 gemm_h(HID / BN, NROWS / BM);

    gemm_f32<<<gemm_d, blk, 0, stream>>>(x, q_w, nullptr, U, NROWS, DIM, DIM);
    lnlif_old<DIM><<<NROWS, blk, 0, stream>>>(U, q_g, q_b, 2.0f, nullptr, Sq);
    gemm_f32<<<gemm_d, blk, 0, stream>>>(x, k_w, nullptr, U, NROWS, DIM, DIM);
    lnlif_old<DIM><<<NROWS, blk, 0, stream>>>(U, k_g, k_b, 2.0f, nullptr, Sk);
    gemm_f32<<<gemm_d, blk, 0, stream>>>(x, v_w, nullptr, U, NROWS, DIM, DIM);
    lnlif_old<DIM><<<NROWS, blk, 0, stream>>>(U, v_g, v_b, 2.0f, nullptr, Sv);

    ktv_f32<<<NB * NH, blk, 0, stream>>>(Sk, Sv, ktvb);
    qktv_f32<<<NB * NH, blk, 0, stream>>>(Sq, ktvb, Yb);

    gemm_f32<<<gemm_d, blk, 0, stream>>>(Yb, proj_w, proj_bias, U, NROWS, DIM, DIM);
    lnlif_old<DIM><<<NROWS, blk, 0, stream>>>(U, proj_g, proj_beta, 2.0f, x, X1);

    gemm_f32<<<gemm_h, blk, 0, stream>>>(X1, fc1_w, fc1_bias, U, NROWS, DIM, HID);
    lnlif_old<HID><<<NROWS, blk, 0, stream>>>(U, fc1_g, fc1_beta, 2.0f, nullptr, U);

    gemm_f32<<<gemm_d, blk, 0, stream>>>(U, fc2_w, fc2_bias, Y2, NROWS, HID, DIM);
    lnlif_old<DIM><<<NROWS, blk, 0, stream>>>(Y2, fc2_g, fc2_beta, 2.0f, X1, outf);
}

// Round 5
// 920.577 us; speedup vs baseline: 1.8036x; 1.2455x over previous
//
#include <hip/hip_runtime.h>
#include <hip/hip_bf16.h>

// Spikformer block on MI355X.
// Fast path: exact bf16-split MFMA GEMMs (fp32 = 3 bf16 planes; 6 products for
// fp32 x fp32, 3 products for binary-spike x fp32) + fused LN+LIF + exact
// sparse spike-attention (0.125 * q @ (k^T @ v), integer counts).
// R5: BK=64 (half the barrier pairs), XOR-swizzled LDS (pre-swizzled global
// source, swizzled ds_read — rule #21), merged q/k/v GEMM (N=3072).
// Fallback path (ws_size too small): round-2 fp32 VALU pipeline (verified).

#define NB 4
#define LL 1024
#define DIM 1024
#define NH 16
#define HDIM 64
#define HID 4096
#define NROWS (NB * LL)

typedef unsigned short u16;
typedef __attribute__((ext_vector_type(8))) short short8v;   // 8 bf16 (4 VGPRs)
typedef __attribute__((ext_vector_type(4))) float f32x4;     // MFMA acc

// ---------------- bf16 split helpers (RNE; split is exact by construction) ---
__device__ __forceinline__ u16 f2bf(float f) {
    unsigned u = __builtin_bit_cast(unsigned, f);
    return (u16)((u + 0x7fffu + ((u >> 16) & 1u)) >> 16);
}
__device__ __forceinline__ float bf2f(u16 h) {
    unsigned u = ((unsigned)h) << 16;
    return __builtin_bit_cast(float, u);
}
__device__ __forceinline__ void split3v(float v, u16& a, u16& b, u16& c) {
    a = f2bf(v);
    float r = v - bf2f(a);
    b = f2bf(r);
    float r2 = r - bf2f(b);
    c = f2bf(r2);
}

// ---------------- split x (f32 [M][K]) -> planes bf16 [M][3K] ----------------
__global__ __launch_bounds__(256) void split3_rows(
    const float* __restrict__ X, u16* __restrict__ Xs, int K)
{
    const int row = blockIdx.y;
    const int c4 = (blockIdx.x * 256 + threadIdx.x) * 4;
    if (c4 >= K) return;
    float4 v = *(const float4*)(X + (size_t)row * K + c4);
    float vv[4] = {v.x, v.y, v.z, v.w};
    u16 h0[4], h1[4], h2[4];
#pragma unroll
    for (int j = 0; j < 4; ++j) split3v(vv[j], h0[j], h1[j], h2[j]);
    u16* base = Xs + (size_t)row * 3 * K + c4;
    *(uint2*)(base + 0 * K) = *(uint2*)h0;
    *(uint2*)(base + 1 * K) = *(uint2*)h1;
    *(uint2*)(base + 2 * K) = *(uint2*)h2;
}

// ------------- split + transpose W (f32 [K][N]) -> Wt bf16 [N][3K] -----------
__global__ __launch_bounds__(256) void split_wt(
    const float* __restrict__ W, u16* __restrict__ Wt, int K, int N, int ldwt)
{
    __shared__ float tile[64][65];   // [n][k], padded
    const int k0 = blockIdx.y * 64, n0 = blockIdx.x * 64;
    const int t = threadIdx.x;
    const int rr = t >> 4;            // 0..15 (k within chunk)
    const int cc = (t & 15) * 4;      // 0..60 (n)
#pragma unroll
    for (int it = 0; it < 4; ++it) {
        const int k = rr + it * 16;
        float4 v = *(const float4*)(W + (size_t)(k0 + k) * N + n0 + cc);
        tile[cc + 0][k] = v.x; tile[cc + 1][k] = v.y;
        tile[cc + 2][k] = v.z; tile[cc + 3][k] = v.w;
    }
    __syncthreads();
    const int n = t >> 2, kc = (t & 3) * 16;
    u16 h0[16], h1[16], h2[16];
#pragma unroll
    for (int j = 0; j < 16; ++j)
        split3v(tile[n][kc + j], h0[j], h1[j], h2[j]);
    u16* base = Wt + (size_t)(n0 + n) * ldwt + k0 + kc;
    *(uint4*)(base + 0 * K)     = ((uint4*)h0)[0];
    *(uint4*)(base + 0 * K + 8) = ((uint4*)h0)[1];
    *(uint4*)(base + 1 * K)     = ((uint4*)h1)[0];
    *(uint4*)(base + 1 * K + 8) = ((uint4*)h1)[1];
    *(uint4*)(base + 2 * K)     = ((uint4*)h2)[0];
    *(uint4*)(base + 2 * K + 8) = ((uint4*)h2)[1];
}

// ---------------- MFMA GEMM: Out(f32) = sum_segs A[:,a+k] * Bt[:,b+k]^T ------
// A bf16 [M][lda] row-major; Bt bf16 [N][ldb] (output-col-major, k contiguous).
// 128xBN_ tile, 4 waves, BK=64, 16x16x32 bf16 MFMA, global_load_lds staging.
// LDS XOR-swizzle: 16B slot s of row r holds logical slot s^(r&7); staging
// pre-swizzles the GLOBAL source column so LDS dest stays linear (rule #21).
struct SegList { int a[6]; int b[6]; int n; };

template <int BN_>
__global__ __launch_bounds__(256) void gemm_mfma(
    const u16* __restrict__ A, int lda,
    const u16* __restrict__ Bt, int ldb,
    SegList segs, int Kseg,
    const float* __restrict__ bias,
    float* __restrict__ Out, int ldo)
{
    constexpr int NF = BN_ / 32;              // B-frags per wave (2 or 4)
    __shared__ u16 As[128 * 64];              // 16 KB
    __shared__ u16 Bs[BN_ * 64];              // 8/16 KB
    const int t = threadIdx.x;
    const int wid = t >> 6, lane = t & 63;
    const int wr = wid >> 1, wc = wid & 1;
    const int row0 = blockIdx.y * 128, col0 = blockIdx.x * BN_;
    const int lrow = lane & 15;
    // staging: chunk = 8 rows x 64 elems (1 KB). lane covers (subrow, slot).
    const int s_subrow = lane >> 3;                       // 0..7
    const int s_slot   = (lane & 7) ^ (lane >> 3);        // pre-swizzled source slot
    const int s_coff   = s_slot * 8;                      // source col offset (elems)

    f32x4 acc[4][NF];
#pragma unroll
    for (int i = 0; i < 4; ++i)
#pragma unroll
        for (int j = 0; j < NF; ++j) acc[i][j] = f32x4{0.f, 0.f, 0.f, 0.f};

    for (int s = 0; s < segs.n; ++s) {
        const u16* pa = A + segs.a[s];
        const u16* pb = Bt + segs.b[s];
        for (int k0 = 0; k0 < Kseg; k0 += 64) {
            // All frag ds_reads of the previous iteration must be retired in
            // EVERY wave before any wave's DMA overwrites LDS.
            asm volatile("s_waitcnt lgkmcnt(0)" ::: "memory");
            __syncthreads();
#pragma unroll
            for (int c = 0; c < 4; ++c) {          // A tile: 16 chunks, 4/wave
                const int chunk = wid * 4 + c;
                const int rg = row0 + chunk * 8 + s_subrow;
                __builtin_amdgcn_global_load_lds(
                    (const __attribute__((address_space(1))) void*)
                        (pa + (size_t)rg * lda + k0 + s_coff),
                    (__attribute__((address_space(3))) void*)
                        (&As[chunk * 512 + lane * 8]),
                    16, 0, 0);
            }
#pragma unroll
            for (int c = 0; c < NF; ++c) {         // B tile: BN_/8 chunks
                const int chunk = wid * NF + c;
                const int rg = col0 + chunk * 8 + s_subrow;
                __builtin_amdgcn_global_load_lds(
                    (const __attribute__((address_space(1))) void*)
                        (pb + (size_t)rg * ldb + k0 + s_coff),
                    (__attribute__((address_space(3))) void*)
                        (&Bs[chunk * 512 + lane * 8]),
                    16, 0, 0);
            }
            // All async LDS-DMA of THIS wave must land before the barrier so
            // that after the barrier every wave sees every wave's staging.
            asm volatile("s_waitcnt vmcnt(0)" ::: "memory");
            __syncthreads();
#pragma unroll
            for (int ksub = 0; ksub < 2; ++ksub) {
                short8v af[4], bfr[NF];
#pragma unroll
                for (int f = 0; f < 4; ++f) {
                    const int ra = wr * 64 + f * 16 + lrow;
                    const int slot = ((lane >> 4) + ksub * 4) ^ (lrow & 7);
                    af[f] = *(const short8v*)&As[ra * 64 + slot * 8];
                }
#pragma unroll
                for (int f = 0; f < NF; ++f) {
                    const int rb = wc * (BN_ / 2) + f * 16 + lrow;
                    const int slot = ((lane >> 4) + ksub * 4) ^ (lrow & 7);
                    bfr[f] = *(const short8v*)&Bs[rb * 64 + slot * 8];
                }
#pragma unroll
                for (int i = 0; i < 4; ++i)
#pragma unroll
                    for (int j = 0; j < NF; ++j)
                        acc[i][j] = __builtin_amdgcn_mfma_f32_16x16x32_bf16(
                            af[i], bfr[j], acc[i][j], 0, 0, 0);
            }
        }
    }
    // epilogue: C/D layout col=lane&15, row=(lane>>4)*4+reg  [m89-verified]
#pragma unroll
    for (int j = 0; j < NF; ++j) {
        const int col = col0 + wc * (BN_ / 2) + j * 16 + lrow;
        const float bv = bias ? bias[col] : 0.f;
#pragma unroll
        for (int i = 0; i < 4; ++i) {
            const int rbase = row0 + wr * 64 + i * 16 + (lane >> 4) * 4;
#pragma unroll
            for (int r = 0; r < 4; ++r)
                Out[(size_t)(rbase + r) * ldo + col] = acc[i][j][r] + bv;
        }
    }
}

// ---------------- fused LN + LIF, multi-output ------------------------------
// spike = (LN(u)*g+beta >= 2.0). U row base = r*ld + coloff (supports the
// merged-qkv [4096][3072] output). Optional outputs: spike bf16; f32
// resid+spike; 3-plane bf16 split of resid+spike.
template <int DN>
__global__ __launch_bounds__(256) void lnlif2(
    const float* __restrict__ U, int ld, int coloff,
    const float* __restrict__ g, const float* __restrict__ beta,
    const float* __restrict__ resid,
    u16* __restrict__ spike_bf16,
    float* __restrict__ out_f32,
    u16* __restrict__ split3_out)
{
    constexpr int PT = DN / 256;
    const int r = blockIdx.x, t = threadIdx.x;
    const float* u = U + (size_t)r * ld + coloff;
    float vals[PT];
    float lsum = 0.f;
#pragma unroll
    for (int i = 0; i < PT; ++i) { vals[i] = u[t + i * 256]; lsum += vals[i]; }
    __shared__ float red[4];
    __shared__ float bcast;
    for (int o = 32; o > 0; o >>= 1) lsum += __shfl_down(lsum, o);
    if ((t & 63) == 0) red[t >> 6] = lsum;
    __syncthreads();
    if (t == 0) bcast = (red[0] + red[1] + red[2] + red[3]) * (1.f / DN);
    __syncthreads();
    const float m = bcast;
    float lss = 0.f;
#pragma unroll
    for (int i = 0; i < PT; ++i) { float d = vals[i] - m; lss += d * d; }
    for (int o = 32; o > 0; o >>= 1) lss += __shfl_down(lss, o);
    if ((t & 63) == 0) red[t >> 6] = lss;
    __syncthreads();
    if (t == 0) bcast = (red[0] + red[1] + red[2] + red[3]) * (1.f / DN);
    __syncthreads();
    const float rs = 1.f / sqrtf(bcast + 1e-5f);
#pragma unroll
    for (int i = 0; i < PT; ++i) {
        const int c = t + i * 256;
        const size_t idx = (size_t)r * DN + c;
        const float nrm = (vals[i] - m) * rs * g[c] + beta[c];
        const float s = (nrm >= 2.0f) ? 1.0f : 0.0f;
        if (spike_bf16) spike_bf16[idx] = s != 0.f ? (u16)0x3F80 : (u16)0;
        if (out_f32 || split3_out) {
            const float v = (resid ? resid[idx] : 0.f) + s;
            if (out_f32) out_f32[idx] = v;
            if (split3_out) {
                u16 h0, h1, h2; split3v(v, h0, h1, h2);
                split3_out[(size_t)r * 3 * DN + 0 * DN + c] = h0;
                split3_out[(size_t)r * 3 * DN + 1 * DN + c] = h1;
                split3_out[(size_t)r * 3 * DN + 2 * DN + c] = h2;
            }
        }
    }
}

// ---------------- attention: ktv (bf16 spikes) ------------------------------
__global__ __launch_bounds__(256) void ktv_bf16(
    const u16* __restrict__ Sk, const u16* __restrict__ Sv,
    float* __restrict__ ktvb)
{
    const int bh = blockIdx.x;
    const int b = bh >> 4, h = bh & 15;
    __shared__ float kch[64][64];
    __shared__ float vch[64][64];
    const int t = threadIdx.x;
    const int i = t >> 2;
    const int j0 = (t & 3) << 4;
    float4 a0 = {0,0,0,0}, a1 = {0,0,0,0}, a2 = {0,0,0,0}, a3 = {0,0,0,0};
    for (int l0 = 0; l0 < LL; l0 += 64) {
        __syncthreads();
#pragma unroll
        for (int q = 0; q < 2; ++q) {
            const int chunk = t + q * 256;           // 512 chunks of 8 elems
            const int li = chunk >> 3, c8 = (chunk & 7) << 3;
            const size_t off = ((size_t)b * LL + l0 + li) * DIM + h * HDIM + c8;
            union { uint4 v; u16 s[8]; } uk, uv;
            uk.v = *(const uint4*)(Sk + off);
            uv.v = *(const uint4*)(Sv + off);
#pragma unroll
            for (int j = 0; j < 8; ++j) {
                kch[li][c8 + j] = uk.s[j] ? 1.f : 0.f;
                vch[li][c8 + j] = uv.s[j] ? 1.f : 0.f;
            }
        }
        __syncthreads();
        for (int l = 0; l < 64; ++l) {
            if (kch[l][i] != 0.f) {
                const float4 v0 = *(float4*)&vch[l][j0];
                const float4 v1 = *(float4*)&vch[l][j0 + 4];
                const float4 v2 = *(float4*)&vch[l][j0 + 8];
                const float4 v3 = *(float4*)&vch[l][j0 + 12];
                a0.x += v0.x; a0.y += v0.y; a0.z += v0.z; a0.w += v0.w;
                a1.x += v1.x; a1.y += v1.y; a1.z += v1.z; a1.w += v1.w;
                a2.x += v2.x; a2.y += v2.y; a2.z += v2.z; a2.w += v2.w;
                a3.x += v3.x; a3.y += v3.y; a3.z += v3.z; a3.w += v3.w;
            }
        }
    }
    const size_t o = ((size_t)bh * 64 + i) * 64 + j0;
    *(float4*)(ktvb + o)      = a0;
    *(float4*)(ktvb + o + 4)  = a1;
    *(float4*)(ktvb + o + 8)  = a2;
    *(float4*)(ktvb + o + 12) = a3;
}

// ---------------- attention: q@(ktv), LIF(v_th=0.5), bf16 spikes out --------
__global__ __launch_bounds__(256) void qktv_bf16(
    const u16* __restrict__ Sq, const float* __restrict__ ktvb,
    u16* __restrict__ Y)
{
    const int bh = blockIdx.x;
    const int b = bh >> 4, h = bh & 15;
    __shared__ float kt[64][64];
    const int t = threadIdx.x;
#pragma unroll
    for (int q = 0; q < 16; ++q) {
        const int idx = t + q * 256;
        ((float*)kt)[idx] = ktvb[(size_t)bh * 4096 + idx];
    }
    __syncthreads();
    const int li = t >> 6;
    const int j = t & 63;
    for (int l0 = 0; l0 < LL; l0 += 4) {
        const size_t roff = ((size_t)b * LL + l0 + li) * DIM + h * HDIM;
        const u16 sqv = Sq[roff + j];
        unsigned long long mask = __ballot(sqv != 0);
        float acc = 0.f;
        while (mask) {
            const int i = __ffsll((unsigned long long)mask) - 1;
            mask &= mask - 1;
            acc += kt[i][j];
        }
        const float y = 0.125f * acc;
        Y[roff + j] = (y >= 1.0f) ? (u16)0x3F80 : (u16)0;
    }
}

// ======================= FALLBACK (round-2 fp32 path) ========================
#define BM 128
#define BN 128
#define BK 16

__global__ __launch_bounds__(256) void gemm_f32(
    const float* __restrict__ A, const float* __restrict__ W,
    const float* __restrict__ bias, float* __restrict__ U,
    int M, int K, int N)
{
    __shared__ float As[BK][BM];
    __shared__ float Bs[BK][BN];
    const int t = threadIdx.x;
    const int tx = t & 15, ty = t >> 4;
    const int row0 = blockIdx.y * BM, col0 = blockIdx.x * BN;
    const int ar = t >> 2;
    const int ac = (t & 3) << 2;
    const int br = t >> 5;
    const int bc = (t & 31) << 2;
    float acc[8][8];
#pragma unroll
    for (int i = 0; i < 8; ++i)
#pragma unroll
        for (int j = 0; j < 8; ++j) acc[i][j] = 0.f;
    for (int k0 = 0; k0 < K; k0 += BK) {
        float4 va0 = *(const float4*)(A + (size_t)(row0 + ar) * K + k0 + ac);
        float4 va1 = *(const float4*)(A + (size_t)(row0 + ar + 64) * K + k0 + ac);
        float4 vb0 = *(const float4*)(W + (size_t)(k0 + br) * N + col0 + bc);
        float4 vb1 = *(const float4*)(W + (size_t)(k0 + br + 8) * N + col0 + bc);
        __syncthreads();
        As[ac + 0][ar] = va0.x; As[ac + 1][ar] = va0.y;
        As[ac + 2][ar] = va0.z; As[ac + 3][ar] = va0.w;
        As[ac + 0][ar + 64] = va1.x; As[ac + 1][ar + 64] = va1.y;
        As[ac + 2][ar + 64] = va1.z; As[ac + 3][ar + 64] = va1.w;
        *(float4*)&Bs[br][bc] = vb0;
        *(float4*)&Bs[br + 8][bc] = vb1;
        __syncthreads();
#pragma unroll
        for (int kk = 0; kk < BK; ++kk) {
            float4 fa0 = *(float4*)&As[kk][ty * 8];
            float4 fa1 = *(float4*)&As[kk][ty * 8 + 4];
            float4 fb0 = *(float4*)&Bs[kk][tx * 8];
            float4 fb1 = *(float4*)&Bs[kk][tx * 8 + 4];
            float av[8] = {fa0.x, fa0.y, fa0.z, fa0.w, fa1.x, fa1.y, fa1.z, fa1.w};
            float bv[8] = {fb0.x, fb0.y, fb0.z, fb0.w, fb1.x, fb1.y, fb1.z, fb1.w};
#pragma unroll
            for (int i = 0; i < 8; ++i)
#pragma unroll
                for (int j = 0; j < 8; ++j)
                    acc[i][j] += av[i] * bv[j];
        }
    }
    float bvals[8];
#pragma unroll
    for (int j = 0; j < 8; ++j)
        bvals[j] = bias ? bias[col0 + tx * 8 + j] : 0.f;
#pragma unroll
    for (int i = 0; i < 8; ++i) {
        const int row = row0 + ty * 8 + i;
        float* dst = U + (size_t)row * N + col0 + tx * 8;
        float4 o0, o1;
        o0.x = acc[i][0] + bvals[0]; o0.y = acc[i][1] + bvals[1];
        o0.z = acc[i][2] + bvals[2]; o0.w = acc[i][3] + bvals[3];
        o1.x = acc[i][4] + bvals[4]; o1.y = acc[i][5] + bvals[5];
        o1.z = acc[i][6] + bvals[6]; o1.w = acc[i][7] + bvals[7];
        *(float4*)dst = o0;
        *(float4*)(dst + 4) = o1;
    }
}

template <int DN>
__global__ __launch_bounds__(256) void lnlif_old(
    const float* __restrict__ U, const float* __restrict__ g,
    const float* __restrict__ beta, float thr,
    const float* __restrict__ resid, float* __restrict__ out)
{
    constexpr int PT = DN / 256;
    const int r = blockIdx.x, t = threadIdx.x;
    const float* u = U + (size_t)r * DN;
    float vals[PT];
    float lsum = 0.f;
#pragma unroll
    for (int i = 0; i < PT; ++i) { vals[i] = u[t + i * 256]; lsum += vals[i]; }
    __shared__ float red[4];
    __shared__ float bc0;
    for (int o = 32; o > 0; o >>= 1) lsum += __shfl_down(lsum, o);
    if ((t & 63) == 0) red[t >> 6] = lsum;
    __syncthreads();
    if (t == 0) bc0 = (red[0] + red[1] + red[2] + red[3]) * (1.f / DN);
    __syncthreads();
    const float m = bc0;
    float lss = 0.f;
#pragma unroll
    for (int i = 0; i < PT; ++i) { float d = vals[i] - m; lss += d * d; }
    for (int o = 32; o > 0; o >>= 1) lss += __shfl_down(lss, o);
    if ((t & 63) == 0) red[t >> 6] = lss;
    __syncthreads();
    if (t == 0) bc0 = (red[0] + red[1] + red[2] + red[3]) * (1.f / DN);
    __syncthreads();
    const float rs = 1.0f / sqrtf(bc0 + 1e-5f);
#pragma unroll
    for (int i = 0; i < PT; ++i) {
        const int c = t + i * 256;
        const float nrm = (vals[i] - m) * rs * g[c] + beta[c];
        const float s = (nrm >= thr) ? 1.0f : 0.0f;
        out[(size_t)r * DN + c] = resid ? (resid[(size_t)r * DN + c] + s) : s;
    }
}

__global__ __launch_bounds__(256) void ktv_f32(
    const float* __restrict__ Sk, const float* __restrict__ Sv,
    float* __restrict__ ktvb)
{
    const int bh = blockIdx.x;
    const int b = bh >> 4, h = bh & 15;
    __shared__ float kch[64][64];
    __shared__ float vch[64][64];
    const int t = threadIdx.x;
    const int i = t >> 2;
    const int j0 = (t & 3) << 4;
    float4 a0 = {0,0,0,0}, a1 = {0,0,0,0}, a2 = {0,0,0,0}, a3 = {0,0,0,0};
    for (int l0 = 0; l0 < LL; l0 += 64) {
        __syncthreads();
#pragma unroll
        for (int q = 0; q < 4; ++q) {
            const int idx = t + q * 256;
            const int li = idx >> 4, c4 = (idx & 15) << 2;
            const size_t off = ((size_t)b * LL + l0 + li) * DIM + h * HDIM + c4;
            *(float4*)&kch[li][c4] = *(const float4*)(Sk + off);
            *(float4*)&vch[li][c4] = *(const float4*)(Sv + off);
        }
        __syncthreads();
        for (int l = 0; l < 64; ++l) {
            if (kch[l][i] != 0.f) {
                const float4 v0 = *(float4*)&vch[l][j0];
                const float4 v1 = *(float4*)&vch[l][j0 + 4];
                const float4 v2 = *(float4*)&vch[l][j0 + 8];
                const float4 v3 = *(float4*)&vch[l][j0 + 12];
                a0.x += v0.x; a0.y += v0.y; a0.z += v0.z; a0.w += v0.w;
                a1.x += v1.x; a1.y += v1.y; a1.z += v1.z; a1.w += v1.w;
                a2.x += v2.x; a2.y += v2.y; a2.z += v2.z; a2.w += v2.w;
                a3.x += v3.x; a3.y += v3.y; a3.z += v3.z; a3.w += v3.w;
            }
        }
    }
    const size_t o = ((size_t)bh * 64 + i) * 64 + j0;
    *(float4*)(ktvb + o)      = a0;
    *(float4*)(ktvb + o + 4)  = a1;
    *(float4*)(ktvb + o + 8)  = a2;
    *(float4*)(ktvb + o + 12) = a3;
}

__global__ __launch_bounds__(256) void qktv_f32(
    const float* __restrict__ Sq, const float* __restrict__ ktvb,
    float* __restrict__ Y)
{
    const int bh = blockIdx.x;
    const int b = bh >> 4, h = bh & 15;
    __shared__ float kt[64][64];
    const int t = threadIdx.x;
#pragma unroll
    for (int q = 0; q < 16; ++q) {
        const int idx = t + q * 256;
        ((float*)kt)[idx] = ktvb[(size_t)bh * 4096 + idx];
    }
    __syncthreads();
    const int li = t >> 6;
    const int j = t & 63;
    for (int l0 = 0; l0 < LL; l0 += 4) {
        const size_t roff = ((size_t)b * LL + l0 + li) * DIM + h * HDIM;
        const float sqv = Sq[roff + j];
        unsigned long long mask = __ballot(sqv != 0.f);
        float acc = 0.f;
        while (mask) {
            const int i = __ffsll((unsigned long long)mask) - 1;
            mask &= mask - 1;
            acc += kt[i][j];
        }
        const float y = 0.125f * acc;
        Y[roff + j] = (y >= 1.0f) ? 1.0f : 0.0f;
    }
}

// ============================== launch ======================================
extern "C" void kernel_launch(void* const* d_in, const int* in_sizes, int n_in,
                              void* d_out, int out_size, void* d_ws, size_t ws_size,
                              hipStream_t stream)
{
    const float* x        = (const float*)d_in[0];
    const float* q_w      = (const float*)d_in[1];
    const float* q_g      = (const float*)d_in[2];
    const float* q_b      = (const float*)d_in[3];
    const float* k_w      = (const float*)d_in[4];
    const float* k_g      = (const float*)d_in[5];
    const float* k_b      = (const float*)d_in[6];
    const float* v_w      = (const float*)d_in[7];
    const float* v_g      = (const float*)d_in[8];
    const float* v_b      = (const float*)d_in[9];
    const float* proj_w   = (const float*)d_in[10];
    const float* proj_bias= (const float*)d_in[11];
    const float* proj_g   = (const float*)d_in[12];
    const float* proj_beta= (const float*)d_in[13];
    const float* fc1_w    = (const float*)d_in[14];
    const float* fc1_bias = (const float*)d_in[15];
    const float* fc1_g    = (const float*)d_in[16];
    const float* fc1_beta = (const float*)d_in[17];
    const float* fc2_w    = (const float*)d_in[18];
    const float* fc2_bias = (const float*)d_in[19];
    const float* fc2_g    = (const float*)d_in[20];
    const float* fc2_beta = (const float*)d_in[21];

    const dim3 blk(256);
    const size_t NEEDED = 143654912;  // see layout below

    if (ws_size >= NEEDED) {
        // ---- fast path layout (bytes):
        //   U    f32  [0, 67108864)        GEMM outputs (48MB merged-qkv, 64MB fc1)
        //   Xsh  bf16 [67108864, +33554432) Xs planes / X1s planes / fc1 spikes
        //   Wbuf bf16 [100663296, +25165824) weight planes (qkv merged 18MB,
        //                                    fc1 24MB, fc2 24MB)
        //   Sq   bf16 [125829120, +8388608)
        //   Sk   bf16 [134217728, +8388608)
        //   ktvb f32  [142606336, +1048576)
        //   SvYb bf16 = Xsh + 25165824 (spare 8 MB above Xs/X1s planes)
        //   X1   f32  = d_out (overwritten element-wise by final lnlif)
        char* ws = (char*)d_ws;
        float* U    = (float*)ws;
        u16*   Xsh  = (u16*)(ws + 67108864);
        u16*   Wbuf = (u16*)(ws + 100663296);
        u16*   Sq   = (u16*)(ws + 125829120);
        u16*   Sk   = (u16*)(ws + 134217728);
        float* ktvb = (float*)(ws + 142606336);
        u16*   SvYb = (u16*)((char*)Xsh + 25165824);
        u16*   Xs   = Xsh;          // [4096][3072]
        u16*   X1s  = Xsh;          // [4096][3072] (after Xs dead)
        u16*   Sm   = Xsh;          // [4096][4096] (after X1s dead)
        float* X1   = (float*)d_out;

        SegList segX;  // 6-product exact fp32xfp32: (0,0)(1,1)(2,0)(0,2)(1,0)(0,1)
        {
            const int pa[6] = {0, 1, 2, 0, 1, 0}, pb[6] = {0, 1, 0, 2, 0, 1};
            for (int i = 0; i < 6; ++i) { segX.a[i] = pa[i] * 1024; segX.b[i] = pb[i] * 1024; }
            segX.n = 6;
        }
        SegList segP;  // spike x fp32 (K=1024): A plane 0, B planes 0/1/2
        {
            for (int i = 0; i < 6; ++i) { segP.a[i] = 0; segP.b[i] = 0; }
            segP.b[1] = 1024; segP.b[2] = 2048; segP.n = 3;
        }
        SegList segF2; // spike x fp32 (K=4096)
        {
            for (int i = 0; i < 6; ++i) { segF2.a[i] = 0; segF2.b[i] = 0; }
            segF2.b[1] = 4096; segF2.b[2] = 8192; segF2.n = 3;
        }

        split3_rows<<<dim3(1, NROWS), blk, 0, stream>>>(x, Xs, DIM);

        // merged q|k|v: Wt rows 0..1023 = q, 1024..2047 = k, 2048..3071 = v
        split_wt<<<dim3(16, 16), blk, 0, stream>>>(q_w, Wbuf,                  DIM, DIM, 3072);
        split_wt<<<dim3(16, 16), blk, 0, stream>>>(k_w, Wbuf + 1024 * 3072,    DIM, DIM, 3072);
        split_wt<<<dim3(16, 16), blk, 0, stream>>>(v_w, Wbuf + 2048 * 3072,    DIM, DIM, 3072);
        gemm_mfma<64><<<dim3(48, 32), blk, 0, stream>>>(Xs, 3072, Wbuf, 3072, segX, 1024, nullptr, U, 3072);
        lnlif2<DIM><<<NROWS, blk, 0, stream>>>(U, 3072, 0,    q_g, q_b, nullptr, Sq,   nullptr, nullptr);
        lnlif2<DIM><<<NROWS, blk, 0, stream>>>(U, 3072, 1024, k_g, k_b, nullptr, Sk,   nullptr, nullptr);
        lnlif2<DIM><<<NROWS, blk, 0, stream>>>(U, 3072, 2048, v_g, v_b, nullptr, SvYb, nullptr, nullptr);

        // attention (exact): ktv counts, then 0.125*q@ktv, LIF v_th=0.5
        ktv_bf16<<<NB * NH, blk, 0, stream>>>(Sk, SvYb, ktvb);
        qktv_bf16<<<NB * NH, blk, 0, stream>>>(Sq, ktvb, SvYb);   // Yb aliases Sv

        // proj + LN + LIF; residual-1 into d_out (X1) + 3-plane split (X1s)
        split_wt<<<dim3(16, 16), blk, 0, stream>>>(proj_w, Wbuf, DIM, DIM, 3072);
        gemm_mfma<64><<<dim3(16, 32), blk, 0, stream>>>(SvYb, 1024, Wbuf, 3072, segP, 1024, proj_bias, U, DIM);
        lnlif2<DIM><<<NROWS, blk, 0, stream>>>(U, DIM, 0, proj_g, proj_beta, x, nullptr, X1, X1s);

        // fc1 + LN + LIF (spikes bf16 into Sm, overwrites X1s)
        split_wt<<<dim3(64, 16), blk, 0, stream>>>(fc1_w, Wbuf, DIM, HID, 3072);
        gemm_mfma<128><<<dim3(32, 32), blk, 0, stream>>>(X1s, 3072, Wbuf, 3072, segX, 1024, fc1_bias, U, HID);
        lnlif2<HID><<<NROWS, blk, 0, stream>>>(U, HID, 0, fc1_g, fc1_beta, nullptr, Sm, nullptr, nullptr);

        // fc2 + LN + LIF + residual-2 -> d_out
        split_wt<<<dim3(16, 64), blk, 0, stream>>>(fc2_w, Wbuf, HID, DIM, 12288);
        gemm_mfma<64><<<dim3(16, 32), blk, 0, stream>>>(Sm, 4096, Wbuf, 12288, segF2, 4096, fc2_bias, U, DIM);
        lnlif2<DIM><<<NROWS, blk, 0, stream>>>(U, DIM, 0, fc2_g, fc2_beta, X1, nullptr, (float*)d_out, nullptr);
        return;
    }

    // ---- fallback: round-2 fp32 path (verified; needs ~85 MB) ----
    float* U    = (float*)d_ws;
    float* Sq   = U + (size_t)1 * NROWS * DIM;
    float* Sk   = U + (size_t)2 * NROWS * DIM;
    float* Sv   = U + (size_t)3 * NROWS * DIM;
    float* Yb   = Sv;
    float* ktvb = U + (size_t)NROWS * HID;
    float* Y2   = ktvb + (size_t)NB * NH * HDIM * HDIM;
    float* X1   = (float*)d_out;
    float* outf = (float*)d_out;

    const dim3 gemm_d(DIM / BN, NROWS / BM);
    const dim3 gemm_h(HID / BN, NROWS / BM);

    gemm_f32<<<gemm_d, blk, 0, stream>>>(x, q_w, nullptr, U, NROWS, DIM, DIM);
    lnlif_old<DIM><<<NROWS, blk, 0, stream>>>(U, q_g, q_b, 2.0f, nullptr, Sq);
    gemm_f32<<<gemm_d, blk, 0, stream>>>(x, k_w, nullptr, U, NROWS, DIM, DIM);
    lnlif_old<DIM><<<NROWS, blk, 0, stream>>>(U, k_g, k_b, 2.0f, nullptr, Sk);
    gemm_f32<<<gemm_d, blk, 0, stream>>>(x, v_w, nullptr, U, NROWS, DIM, DIM);
    lnlif_old<DIM><<<NROWS, blk, 0, stream>>>(U, v_g, v_b, 2.0f, nullptr, Sv);

    ktv_f32<<<NB * NH, blk, 0, stream>>>(Sk, Sv, ktvb);
    qktv_f32<<<NB * NH, blk, 0, stream>>>(Sq, ktvb, Yb);

    gemm_f32<<<gemm_d, blk, 0, stream>>>(Yb, proj_w, proj_bias, U, NROWS, DIM, DIM);
    lnlif_old<DIM><<<NROWS, blk, 0, stream>>>(U, proj_g, proj_beta, 2.0f, x, X1);

    gemm_f32<<<gemm_h, blk, 0, stream>>>(X1, fc1_w, fc1_bias, U, NROWS, DIM, HID);
    lnlif_old<HID><<<NROWS, blk, 0, stream>>>(U, fc1_g, fc1_beta, 2.0f, nullptr, U);

    gemm_f32<<<gemm_d, blk, 0, stream>>>(U, fc2_w, fc2_bias, Y2, NROWS, HID, DIM);
    lnlif_old<DIM><<<NROWS, blk, 0, stream>>>(Y2, fc2_g, fc2_beta, 2.0f, X1, outf);
}